// Round 6
// baseline (4006.899 us; speedup 1.0000x reference)
//
#include <hip/hip_runtime.h>
#include <cmath>

using bf16 = __bf16;
typedef __bf16 bf16x8 __attribute__((ext_vector_type(8)));
typedef float f32x4 __attribute__((ext_vector_type(4)));

#define N_LAYER 12
#define EMB 768
#define E3 2304
#define FF 3072
#define SEQ 512
#define NB 8
#define BT 4096
#define NH 12
#define HD 64
#define VOC 60
#define DST 128

// ---------------- async global->LDS, 16B per lane ----------------
__device__ __forceinline__ void gll16(const bf16* g, bf16* l) {
    __builtin_amdgcn_global_load_lds(
        (const __attribute__((address_space(1))) void*)g,
        (__attribute__((address_space(3))) void*)l,
        16, 0, 0);
}

// ---------------- state scan ----------------
__global__ __launch_bounds__(1024)
void scan_kernel(const int* __restrict__ ids, const int* __restrict__ mul, int* __restrict__ pre)
{
    __shared__ int smul[VOC * VOC];
    __shared__ int sx[SEQ];
    __shared__ int chunk_end[16 * VOC];
    __shared__ int entry[17];
    int b = blockIdx.x;
    int tid = threadIdx.x;
    for (int i = tid; i < VOC * VOC; i += 1024) smul[i] = mul[i];
    for (int i = tid; i < SEQ; i += 1024) sx[i] = ids[b * SEQ + i];
    __syncthreads();
    if (tid < 16 * VOC) {
        int c = tid / VOC, s0 = tid % VOC;
        int s = s0;
        int base = c * 32;
        for (int j = 0; j < 32; j++) s = smul[sx[base + j] * VOC + s];
        chunk_end[c * VOC + s0] = s;
    }
    __syncthreads();
    if (tid == 0) {
        int s = 0; // ID_ID
        entry[0] = 0;
        for (int c = 0; c < 16; c++) { s = chunk_end[c * VOC + s]; entry[c + 1] = s; }
    }
    __syncthreads();
    if (tid < 16) {
        int c = tid;
        int s = entry[c];
        for (int j = 0; j < 32; j++) {
            int t = c * 32 + j;
            pre[b * SEQ + t] = s;
            s = smul[sx[t] * VOC + s];
        }
    }
}

// ---------------- state-emb projection table: pst[v][e] ----------------
__global__ __launch_bounds__(256)
void pst_kernel(const float* __restrict__ se, const float* __restrict__ w,
                const float* __restrict__ bias, float* __restrict__ pst)
{
    int v = blockIdx.x;
    int e = blockIdx.y * 256 + threadIdx.x;
    float acc = bias[e];
    for (int k = 0; k < DST; k++) acc += se[v * DST + k] * w[k * EMB + e];
    pst[v * EMB + e] = acc;
}

// ---------------- cross-wave LN stats reduce helper (256 threads) ----------------
__device__ __forceinline__ void ln_stats(float& s, float& s2, float* ps, int tid)
{
    for (int o = 32; o > 0; o >>= 1) { s += __shfl_xor(s, o, 64); s2 += __shfl_xor(s2, o, 64); }
    int wave = tid >> 6, lane = tid & 63;
    if (lane == 0) { ps[wave] = s; ps[4 + wave] = s2; }
    __syncthreads();
    s = ps[0] + ps[1] + ps[2] + ps[3];
    s2 = ps[4] + ps[5] + ps[6] + ps[7];
}

// ---------------- fused embedding + LN: h, xb = LN(emb) ----------------
__global__ __launch_bounds__(256)
void embed_ln_kernel(const int* __restrict__ ids, const int* __restrict__ pre,
                     const float* __restrict__ tok_emb, const float* __restrict__ pst,
                     const float* __restrict__ wpe,
                     const float* __restrict__ g, const float* __restrict__ b,
                     float* __restrict__ h, bf16* __restrict__ y)
{
    int t = blockIdx.x;                 // token index
    int pos = t & (SEQ - 1);
    int id = ids[t], pr = pre[t];
    int tid = threadIdx.x;
    float vals[3];
    float s = 0.f, s2 = 0.f;
    for (int j = 0; j < 3; j++) {
        int e = tid + j * 256;
        float xv = tok_emb[id * EMB + e] + pst[pr * EMB + e] + wpe[pos * EMB + e];
        h[(size_t)t * EMB + e] = xv;
        vals[j] = xv; s += xv; s2 += xv * xv;
    }
    __shared__ float ps[8];
    ln_stats(s, s2, ps, tid);
    float m = s * (1.0f / EMB);
    float var = s2 * (1.0f / EMB) - m * m;
    float inv = rsqrtf(var + 1e-5f);
    for (int j = 0; j < 3; j++) {
        int e = tid + j * 256;
        y[(size_t)t * EMB + e] = (bf16)((vals[j] - m) * inv * g[e] + b[e]);
    }
}

// ---------------- fused split-K reduce + residual + LN ----------------
template<int S>
__global__ __launch_bounds__(256)
void reduce_ln_kernel(const float* __restrict__ p, const float* __restrict__ bias,
                      float* __restrict__ h,
                      const float* __restrict__ g, const float* __restrict__ b,
                      bf16* __restrict__ y)
{
    int t = blockIdx.x;
    int tid = threadIdx.x;
    float vals[3];
    float s = 0.f, s2 = 0.f;
    for (int j = 0; j < 3; j++) {
        int e = tid + j * 256;
        size_t i = (size_t)t * EMB + e;
        float acc = bias[e] + h[i];
        for (int sp = 0; sp < S; sp++) acc += p[(size_t)sp * ((size_t)BT * EMB) + i];
        h[i] = acc;
        vals[j] = acc; s += acc; s2 += acc * acc;
    }
    __shared__ float ps[8];
    ln_stats(s, s2, ps, tid);
    float m = s * (1.0f / EMB);
    float var = s2 * (1.0f / EMB) - m * m;
    float inv = rsqrtf(var + 1e-5f);
    for (int j = 0; j < 3; j++) {
        int e = tid + j * 256;
        y[(size_t)t * EMB + e] = (bf16)((vals[j] - m) * inv * g[e] + b[e]);
    }
}

// ---------------- weight transpose + fp32->bf16: W[K,N] -> WT[N,K] ----------------
__global__ __launch_bounds__(256)
void convw_kernel(const float* __restrict__ W, bf16* __restrict__ WT, int K, int N)
{
    __shared__ float tile[32][33];
    int kb = blockIdx.y * 32, nb = blockIdx.x * 32;
    const float* Wl = W + (size_t)blockIdx.z * K * N;
    bf16* WTl = WT + (size_t)blockIdx.z * K * N;
    int tx = threadIdx.x & 31, ty = threadIdx.x >> 5; // ty 0..7
    for (int i = ty; i < 32; i += 8) {
        int k = kb + i, n = nb + tx;
        if (k < K && n < N) tile[i][tx] = Wl[(size_t)k * N + n];
    }
    __syncthreads();
    for (int i = ty; i < 32; i += 8) {
        int n = nb + i, k = kb + tx;
        if (k < K && n < N) WTl[(size_t)n * K + k] = (bf16)tile[tx][i];
    }
}

// ---------------- V transpose: qkv -> vT[bh][d][t] ----------------
__global__ __launch_bounds__(256)
void vtrans_kernel(const bf16* __restrict__ qkv, bf16* __restrict__ vT)
{
    int bh = blockIdx.y;
    int b = bh / NH, hh = bh - b * NH;
    int idx = blockIdx.x * 256 + threadIdx.x; // over 64*512
    int d = idx >> 9, t = idx & 511;
    vT[((size_t)bh * HD + d) * SEQ + t] = qkv[((size_t)(b * SEQ + t)) * E3 + 2 * EMB + hh * HD + d];
}

// ---------------- fused flash attention: qkv,vT -> o[B,T,E] (bf16) ----------------
__global__ __launch_bounds__(256)
void fattn_kernel(const bf16* __restrict__ qkv, const bf16* __restrict__ vT, bf16* __restrict__ Og)
{
    __shared__ bf16 sK[128 * 64];
    __shared__ bf16 sV[64 * 128];
    __shared__ bf16 sP[4][16 * 128];
    int mq = blockIdx.x;          // Q tile: rows [mq*64, mq*64+64)
    int bh = blockIdx.y;
    int b = bh / NH, hh = bh - b * NH;
    int tid = threadIdx.x, lane = tid & 63, wave = tid >> 6;
    int r = lane & 15, q = lane >> 4;

    const bf16* Qg = qkv + (size_t)(b * SEQ + mq * 64) * E3 + hh * HD;
    const bf16* Kg = qkv + (size_t)(b * SEQ) * E3 + EMB + hh * HD;
    const bf16* Vg = vT + (size_t)bh * HD * SEQ;

    bf16x8 af[2];
    {
        const bf16* qrow = Qg + (size_t)(wave * 16 + r) * E3 + q * 8;
        af[0] = *(const bf16x8*)(qrow);
        af[1] = *(const bf16x8*)(qrow + 32);
    }

    float mrun[4], lrun[4];
    f32x4 acco[4];
    for (int e = 0; e < 4; e++) { mrun[e] = -1e30f; lrun[e] = 0.f; }
    for (int no = 0; no < 4; no++)
        for (int e = 0; e < 4; e++) acco[no][e] = 0.f;

    int KT = mq / 2 + 1;   // causal: only tiles with cols <= max row
    bf16* sPw = sP[wave];

    for (int kt = 0; kt < KT; kt++) {
        {
            int row = tid >> 3;            // 0..31, 8 lanes/row
            int cb = (tid & 7) * 8;
            for (int rd = 0; rd < 4; rd++) {
                int rr = rd * 32 + row;
                bf16x8 kv = *(const bf16x8*)(Kg + (size_t)(kt * 128 + rr) * E3 + cb);
                *(bf16x8*)(sK + ((rr * 64 + cb) ^ ((rr & 7) << 3))) = kv;
            }
            int rowv = tid >> 4;           // 0..15, 16 lanes/row
            int cbv = (tid & 15) * 8;
            for (int rd = 0; rd < 4; rd++) {
                int rr = rd * 16 + rowv;
                bf16x8 vv = *(const bf16x8*)(Vg + (size_t)rr * SEQ + kt * 128 + cbv);
                *(bf16x8*)(sV + ((rr * 128 + cbv) ^ ((rr & 7) << 3))) = vv;
            }
        }
        __syncthreads();

        f32x4 acc[8];
        for (int ni = 0; ni < 8; ni++)
            for (int e = 0; e < 4; e++) acc[ni][e] = 0.f;
        for (int ks = 0; ks < 2; ks++) {
            for (int ni = 0; ni < 8; ni++) {
                int row = ni * 16 + r;
                bf16x8 bk = *(const bf16x8*)(sK + ((row * 64 + ks * 32 + q * 8) ^ ((row & 7) << 3)));
                acc[ni] = __builtin_amdgcn_mfma_f32_16x16x32_bf16(af[ks], bk, acc[ni], 0, 0, 0);
            }
        }

        bool dm = (kt * 128 + 127) > (mq * 64);
        for (int ni = 0; ni < 8; ni++) {
            int col = kt * 128 + ni * 16 + r;
            for (int e = 0; e < 4; e++) {
                float s = acc[ni][e] * 0.125f;
                if (dm) {
                    int rowg = mq * 64 + wave * 16 + q * 4 + e;
                    if (col > rowg) s = -1e30f;
                }
                acc[ni][e] = s;
            }
        }

        float corr[4];
        for (int e = 0; e < 4; e++) {
            float mx = -1e30f;
            for (int ni = 0; ni < 8; ni++) mx = fmaxf(mx, acc[ni][e]);
            for (int o2 = 1; o2 < 16; o2 <<= 1) mx = fmaxf(mx, __shfl_xor(mx, o2, 64));
            float mn = fmaxf(mrun[e], mx);
            corr[e] = __expf(mrun[e] - mn);
            mrun[e] = mn;
            float ps = 0.f;
            for (int ni = 0; ni < 8; ni++) {
                float p = __expf(acc[ni][e] - mn);
                acc[ni][e] = p;
                ps += p;
            }
            for (int o2 = 1; o2 < 16; o2 <<= 1) ps += __shfl_xor(ps, o2, 64);
            lrun[e] = lrun[e] * corr[e] + ps;
        }
        for (int no = 0; no < 4; no++)
            for (int e = 0; e < 4; e++) acco[no][e] *= corr[e];

        for (int ni = 0; ni < 8; ni++) {
            for (int e = 0; e < 4; e++) {
                int prow = q * 4 + e;
                sPw[(prow * 128 + ni * 16 + r) ^ ((prow & 7) << 3)] = (bf16)acc[ni][e];
            }
        }
        for (int ks2 = 0; ks2 < 4; ks2++) {
            bf16x8 pa = *(const bf16x8*)(sPw + ((r * 128 + ks2 * 32 + q * 8) ^ ((r & 7) << 3)));
            for (int no = 0; no < 4; no++) {
                int row = no * 16 + r;
                bf16x8 bv = *(const bf16x8*)(sV + ((row * 128 + ks2 * 32 + q * 8) ^ ((row & 7) << 3)));
                acco[no] = __builtin_amdgcn_mfma_f32_16x16x32_bf16(pa, bv, acco[no], 0, 0, 0);
            }
        }
        __syncthreads();
    }

    bf16* orow = Og + (size_t)(b * SEQ + mq * 64 + wave * 16) * EMB + hh * HD;
    for (int e = 0; e < 4; e++) {
        float inv = 1.0f / lrun[e];
        for (int no = 0; no < 4; no++)
            orow[(size_t)(q * 4 + e) * EMB + no * 16 + r] = (bf16)(acco[no][e] * inv);
    }
}

// ---------------- head reduce: out = head_b + sum_{s<8} partial[s] ----------------
__global__ __launch_bounds__(256)
void reduce_head_kernel(const float* __restrict__ p, const float* __restrict__ bias,
                        float* __restrict__ out)
{
    int i = blockIdx.x * 256 + threadIdx.x; // over BT*VOC
    int c = i % VOC;
    float acc = bias[c];
    for (int s = 0; s < 8; s++) acc += p[(size_t)s * ((size_t)BT * VOC) + i];
    out[i] = acc;
}

// ================= 256x256 8-phase GEMM, BK=32, 3-buffer, vmcnt(4), XOR-swizzled LDS =================
// LDS layout: logical (row, k-slot q) stored at byte (row*64 + q*16) ^ ((row&7)<<4).
// Staging keeps LDS dest linear (global_load_lds requirement) and pre-swizzles the GLOBAL
// source per lane (rule #21 / m173). Read side applies the same XOR (element ^ ((r&7)<<3)).
// MODE 0: bf16 store (+bias)  MODE 1: bias+gelu->bf16  MODE 6: split-K fp32 partial store
template<int MODE, int KSPLIT = 1>
__global__ __launch_bounds__(512, 2)
void gemm8(const bf16* __restrict__ Ag, const bf16* __restrict__ Bg,
           const float* __restrict__ bias, bf16* __restrict__ Cb, float* __restrict__ Cf,
           int N, int K, int lda, int ldb, int ldc)
{
    // 3 staging buffers x (A[256][32] + B[256][32]) bf16 = 96 KiB; epilogue strips overlay
    __shared__ union {
        bf16 stage[3][2][256 * 32];
        float st[8][16 * 64];
    } sm;

    int zs = blockIdx.z;
    int Kc = K / KSPLIT;
    int kbeg = zs * Kc;
    int NT = Kc / 32;
    if constexpr (MODE == 6) Cf += (size_t)zs * (size_t)BT * ldc;

    int m0 = blockIdx.y * 256, n0 = blockIdx.x * 256;
    int tid = threadIdx.x, lane = tid & 63, wave = tid >> 6;
    int wm = wave >> 2, wn = wave & 3;
    int r = lane & 15, q = lane >> 4;

    f32x4 acc[8][4];
#pragma unroll
    for (int mi = 0; mi < 8; mi++)
#pragma unroll
        for (int ni = 0; ni < 4; ni++)
#pragma unroll
            for (int e = 0; e < 4; e++) acc[mi][ni][e] = 0.f;

    // ---- pre-swizzled staging source: lane l's physical 16B slot holds logical (srow, sq) ----
    // inverse of P = (row*64 + q*16) ^ ((row&7)<<4) over the wave's 16-row chunk:
    int sb   = ((lane >> 2) & 1) ^ ((lane >> 4) & 1);
    int srow = 2 * (lane >> 3) + sb;                       // 0..15 within chunk
    int sq   = (lane & 3) ^ (2 * ((lane >> 3) & 1) + sb);  // 16B slot 0..3
    int scol = sq * 8;                                     // element offset in K
    const bf16* pA0 = Ag + (size_t)(m0 + (wave) * 16 + srow) * lda + scol;
    const bf16* pA1 = Ag + (size_t)(m0 + (8 + wave) * 16 + srow) * lda + scol;
    const bf16* pB0 = Bg + (size_t)(n0 + (wave) * 16 + srow) * ldb + scol;
    const bf16* pB1 = Bg + (size_t)(n0 + (8 + wave) * 16 + srow) * ldb + scol;
    int l0 = wave * 512;        // element offset of wave's chunk-0 (1KB, lane-linear dest)
    int l1 = (8 + wave) * 512;  // chunk-1

    auto stageA = [&](int kt, int b) {
        int k0 = kbeg + kt * 32;
        gll16(pA0 + k0, &sm.stage[b][0][l0]);
        gll16(pA1 + k0, &sm.stage[b][0][l1]);
    };
    auto stageB = [&](int kt, int b) {
        int k0 = kbeg + kt * 32;
        gll16(pB0 + k0, &sm.stage[b][1][l0]);
        gll16(pB1 + k0, &sm.stage[b][1][l1]);
    };

    int rsw = (r & 7) << 3;   // read-side swizzle (element units); row&7 == r&7 for all frags

    // prologue: tiles 0 and 1 (issue order = steady-state order)
    stageA(0, 0); stageB(0, 0);
    stageA(1 < NT ? 1 : 0, 1); stageB(1 < NT ? 1 : 0, 1);
    asm volatile("s_waitcnt vmcnt(4)" ::: "memory");
    __builtin_amdgcn_s_barrier();
    asm volatile("" ::: "memory");

    for (int t = 0; t < NT; t++) {
        int c = t % 3;
        const bf16* la = sm.stage[c][0];
        const bf16* lb = sm.stage[c][1];
        int t2 = (t + 2 < NT) ? t + 2 : NT - 1;   // clamp: dummy stages keep vmcnt math exact
        int b2 = (t + 2) % 3;

        // ---- phase 0: Mfrags 0-3 x Nfrags 0-3 ----
        bf16x8 afr[4], bfr[4];
#pragma unroll
        for (int i = 0; i < 4; i++)
            afr[i] = *(const bf16x8*)(la + (((wm * 128 + i * 16 + r) * 32 + q * 8) ^ rsw));
#pragma unroll
        for (int ni = 0; ni < 4; ni++)
            bfr[ni] = *(const bf16x8*)(lb + (((wn * 64 + ni * 16 + r) * 32 + q * 8) ^ rsw));
        stageA(t2, b2);
        asm volatile("" ::: "memory");
        __builtin_amdgcn_s_barrier();
        __builtin_amdgcn_s_setprio(1);
#pragma unroll
        for (int i = 0; i < 4; i++)
#pragma unroll
            for (int ni = 0; ni < 4; ni++)
                acc[i][ni] = __builtin_amdgcn_mfma_f32_16x16x32_bf16(afr[i], bfr[ni], acc[i][ni], 0, 0, 0);
        __builtin_amdgcn_s_setprio(0);
        asm volatile("" ::: "memory");
        __builtin_amdgcn_s_barrier();
        asm volatile("" ::: "memory");

        // ---- phase 1: Mfrags 4-7 x Nfrags 0-3 (B frags reused) ----
#pragma unroll
        for (int i = 0; i < 4; i++)
            afr[i] = *(const bf16x8*)(la + (((wm * 128 + (4 + i) * 16 + r) * 32 + q * 8) ^ rsw));
        stageB(t2, b2);
        asm volatile("" ::: "memory");
        __builtin_amdgcn_s_barrier();
        __builtin_amdgcn_s_setprio(1);
#pragma unroll
        for (int i = 0; i < 4; i++)
#pragma unroll
            for (int ni = 0; ni < 4; ni++)
                acc[4 + i][ni] = __builtin_amdgcn_mfma_f32_16x16x32_bf16(afr[i], bfr[ni], acc[4 + i][ni], 0, 0, 0);
        __builtin_amdgcn_s_setprio(0);
        // counted wait: allow tile t+2's 4 loads in flight; tile t+1 guaranteed landed after barrier
        asm volatile("s_waitcnt vmcnt(4)" ::: "memory");
        __builtin_amdgcn_s_barrier();
        asm volatile("" ::: "memory");
    }

    // drain in-flight dummy stages before reusing LDS for the epilogue
    asm volatile("s_waitcnt vmcnt(0) lgkmcnt(0)" ::: "memory");
    __builtin_amdgcn_s_barrier();
    asm volatile("" ::: "memory");

    // vectorized epilogue: per-wave 16x64 LDS transpose -> coalesced 16B/lane writes
    float* st = sm.st[wave];
#pragma unroll 1
    for (int mi = 0; mi < 8; mi++) {
#pragma unroll
        for (int ni = 0; ni < 4; ni++)
#pragma unroll
            for (int e = 0; e < 4; e++)
                st[(q * 4 + e) * 64 + ni * 16 + r] = acc[mi][ni][e];
        asm volatile("s_waitcnt lgkmcnt(0)" ::: "memory");
        for (int it = 0; it < 2; it++) {
            int task = lane + it * 64;      // 128 tasks: 16 rows x 8 col-chunks
            int row = task >> 3, cc = (task & 7) * 8;
            f32x4 v0 = *(const f32x4*)(st + row * 64 + cc);
            f32x4 v1 = *(const f32x4*)(st + row * 64 + cc + 4);
            int colg = n0 + wn * 64 + cc;
            int rowg = m0 + wm * 128 + mi * 16 + row;
            if (MODE != 6 && bias) {
                f32x4 b0 = *(const f32x4*)(bias + colg);
                f32x4 b1 = *(const f32x4*)(bias + colg + 4);
                v0 += b0; v1 += b1;
            }
            size_t off = (size_t)rowg * ldc + colg;
            if constexpr (MODE == 0) {
                bf16x8 pk;
                for (int j = 0; j < 4; j++) { pk[j] = (bf16)v0[j]; pk[4 + j] = (bf16)v1[j]; }
                *(bf16x8*)(Cb + off) = pk;
            } else if constexpr (MODE == 1) {
                float w[8];
                for (int j = 0; j < 4; j++) { w[j] = v0[j]; w[4 + j] = v1[j]; }
                bf16x8 pk;
                for (int j = 0; j < 8; j++) {
                    float x = w[j];
                    float gx = 0.5f * x * (1.0f + tanhf(0.7978845608028654f * (x + 0.044715f * x * x * x)));
                    pk[j] = (bf16)gx;
                }
                *(bf16x8*)(Cb + off) = pk;
            } else { // MODE 6: fp32 partial store
                *(f32x4*)(Cf + off) = v0;
                *(f32x4*)(Cf + off + 4) = v1;
            }
        }
        asm volatile("s_waitcnt lgkmcnt(0)" ::: "memory");
    }
}

// ---------------- MFMA GEMM (m97 structure), kept for the head gemm ----------------
// MODE 7: split-K fp32 partial store (scalar path, small N / unaligned ldc)
template<int MODE, int KSPLIT = 1>
__global__ __launch_bounds__(256)
void gemm_bt(const bf16* __restrict__ Ag, const bf16* __restrict__ Bg,
             const float* __restrict__ bias, bf16* __restrict__ Cb, float* __restrict__ Cf,
             int M, int N, int K, int lda, int ldb, int ldc)
{
    __shared__ bf16 sab[2][128 * 32];
    int zs = blockIdx.z % KSPLIT;
    if constexpr (MODE == 7) Cf += (size_t)zs * M * ldc;

    int m0 = blockIdx.y * 128, n0 = blockIdx.x * 128;
    int tid = threadIdx.x, lane = tid & 63, wave = tid >> 6;
    int wm = (wave >> 1) * 64, wn = (wave & 1) * 64;
    int r = lane & 15, q = lane >> 4;

    f32x4 acc[4][4];
    for (int mi = 0; mi < 4; mi++)
        for (int ni = 0; ni < 4; ni++)
            for (int e = 0; e < 4; e++) acc[mi][ni][e] = 0.f;

    bf16* la = sab[0];
    bf16* lb = sab[1];
    int srow = wave * 16 + (lane >> 2);
    int scol = (lane & 3) * 8;
    const bf16* pA = Ag + (size_t)(m0 + srow) * lda + scol;
    const bf16* pB = Bg + (size_t)(n0 + srow) * ldb + scol;
    bf16* lA0 = la + (wave * 16) * 32;
    bf16* lA1 = la + (wave * 16 + 64) * 32;
    bf16* lB0 = lb + (wave * 16) * 32;
    bf16* lB1 = lb + (wave * 16 + 64) * 32;
    size_t stepA = (size_t)64 * lda, stepB = (size_t)64 * ldb;

    int Kc = K / KSPLIT;
    int kbeg = zs * Kc, kend = kbeg + Kc;

    for (int k0 = kbeg; k0 < kend; k0 += 32) {
        gll16(pA + k0, lA0);
        gll16(pA + k0 + stepA, lA1);
        gll16(pB + k0, lB0);
        gll16(pB + k0 + stepB, lB1);
        __syncthreads();
        bf16x8 af[4], bq[4];
        for (int mi = 0; mi < 4; mi++) af[mi] = *(const bf16x8*)(la + (wm + mi * 16 + r) * 32 + q * 8);
        for (int ni = 0; ni < 4; ni++) bq[ni] = *(const bf16x8*)(lb + (wn + ni * 16 + r) * 32 + q * 8);
        for (int mi = 0; mi < 4; mi++)
            for (int ni = 0; ni < 4; ni++)
                acc[mi][ni] = __builtin_amdgcn_mfma_f32_16x16x32_bf16(af[mi], bq[ni], acc[mi][ni], 0, 0, 0);
        __syncthreads();
    }

    // scalar fp32 partial store (small N, unaligned ldc)
    for (int mi = 0; mi < 4; mi++) {
        for (int ni = 0; ni < 4; ni++) {
            int colg = n0 + wn + ni * 16 + r;
            if (colg >= N) continue;
            for (int e = 0; e < 4; e++) {
                int rowg = m0 + wm + mi * 16 + q * 4 + e;
                if (rowg >= M) continue;
                Cf[(size_t)rowg * ldc + colg] = acc[mi][ni][e];
            }
        }
    }
}

extern "C" void kernel_launch(void* const* d_in, const int* in_sizes, int n_in,
                              void* d_out, int out_size, void* d_ws, size_t ws_size,
                              hipStream_t stream)
{
    (void)in_sizes; (void)n_in; (void)out_size; (void)ws_size;
    const int*   input_ids    = (const int*)d_in[0];
    const int*   mul          = (const int*)d_in[1];
    const float* tok_emb      = (const float*)d_in[2];
    const float* state_emb    = (const float*)d_in[3];
    const float* state_proj_w = (const float*)d_in[4];
    const float* state_proj_b = (const float*)d_in[5];
    const float* wpe          = (const float*)d_in[6];
    const float* ln1_g        = (const float*)d_in[7];
    const float* ln1_b        = (const float*)d_in[8];
    const float* attn_w       = (const float*)d_in[9];
    const float* attn_b       = (const float*)d_in[10];
    const float* attn_proj_w  = (const float*)d_in[11];
    const float* attn_proj_b  = (const float*)d_in[12];
    const float* ln2_g        = (const float*)d_in[13];
    const float* ln2_b        = (const float*)d_in[14];
    const float* fc_w         = (const float*)d_in[15];
    const float* fc_b         = (const float*)d_in[16];
    const float* mlp_proj_w   = (const float*)d_in[17];
    const float* mlp_proj_b   = (const float*)d_in[18];
    const float* lnf_g        = (const float*)d_in[19];
    const float* lnf_b        = (const float*)d_in[20];
    const float* head_w       = (const float*)d_in[21];
    const float* head_b       = (const float*)d_in[22];
    float* out = (float*)d_out;

    char* ws = (char*)d_ws;
    size_t off = 0;
    auto alloc = [&](size_t bytes) -> char* {
        char* p = ws + off;
        off += (bytes + 255) & ~(size_t)255;
        return p;
    };
    bf16*  wT_attn = (bf16*)alloc((size_t)N_LAYER * E3 * EMB * 2);
    bf16*  wT_ap   = (bf16*)alloc((size_t)N_LAYER * EMB * EMB * 2);
    bf16*  wT_fc   = (bf16*)alloc((size_t)N_LAYER * FF * EMB * 2);
    bf16*  wT_mp   = (bf16*)alloc((size_t)N_LAYER * EMB * FF * 2);
    bf16*  wT_head = (bf16*)alloc((size_t)VOC * EMB * 2);
    float* pst     = (float*)alloc((size_t)VOC * EMB * 4);
    int*   pre     = (int*)alloc((size_t)BT * 4);
    float* h       = (float*)alloc((size_t)BT * EMB * 4);
    bf16*  xb      = (bf16*)alloc((size_t)BT * EMB * 2);
    bf16*  qkv     = (bf16*)alloc((size_t)BT * E3 * 2);
    bf16*  vT      = (bf16*)alloc((size_t)NB * NH * HD * SEQ * 2);
    bf16*  o       = (bf16*)alloc((size_t)BT * EMB * 2);
    bf16*  fcout   = (bf16*)alloc((size_t)BT * FF * 2);
    float* pbuf    = (float*)alloc((size_t)4 * BT * EMB * 4);  // split-K partials (head: 8*BT*VOC fits too)

    // one-time per call: weight transpose+convert
    convw_kernel<<<dim3(E3 / 32, EMB / 32, N_LAYER), 256, 0, stream>>>(attn_w, wT_attn, EMB, E3);
    convw_kernel<<<dim3(EMB / 32, EMB / 32, N_LAYER), 256, 0, stream>>>(attn_proj_w, wT_ap, EMB, EMB);
    convw_kernel<<<dim3(FF / 32, EMB / 32, N_LAYER), 256, 0, stream>>>(fc_w, wT_fc, EMB, FF);
    convw_kernel<<<dim3(EMB / 32, FF / 32, N_LAYER), 256, 0, stream>>>(mlp_proj_w, wT_mp, FF, EMB);
    convw_kernel<<<dim3(2, EMB / 32, 1), 256, 0, stream>>>(head_w, wT_head, EMB, VOC);

    scan_kernel<<<NB, 1024, 0, stream>>>(input_ids, mul, pre);
    pst_kernel<<<dim3(VOC, 3), 256, 0, stream>>>(state_emb, state_proj_w, state_proj_b, pst);
    // fused embed + ln1(layer 0)
    embed_ln_kernel<<<BT, 256, 0, stream>>>(input_ids, pre, tok_emb, pst, wpe,
                                            ln1_g, ln1_b, h, xb);

    for (int l = 0; l < N_LAYER; l++) {
        // QKV: 256^2 8-phase
        gemm8<0><<<dim3(E3 / 256, BT / 256, 1), 512, 0, stream>>>(
            xb, wT_attn + (size_t)l * E3 * EMB, attn_b + l * E3, qkv, nullptr,
            E3, EMB, EMB, EMB, E3);
        vtrans_kernel<<<dim3(128, NB * NH), 256, 0, stream>>>(qkv, vT);
        fattn_kernel<<<dim3(SEQ / 64, NB * NH), 256, 0, stream>>>(qkv, vT, o);
        // attn proj: 256^2 8-phase split-K x4 -> 192 blocks, fp32 partials
        gemm8<6, 4><<<dim3(EMB / 256, BT / 256, 4), 512, 0, stream>>>(
            o, wT_ap + (size_t)l * EMB * EMB, nullptr, nullptr, pbuf,
            EMB, EMB, EMB, EMB, EMB);
        reduce_ln_kernel<4><<<BT, 256, 0, stream>>>(
            pbuf, attn_proj_b + l * EMB, h, ln2_g + l * EMB, ln2_b + l * EMB, xb);
        // fc + gelu: 256^2 8-phase
        gemm8<1><<<dim3(FF / 256, BT / 256, 1), 512, 0, stream>>>(
            xb, wT_fc + (size_t)l * FF * EMB, fc_b + l * FF, fcout, nullptr,
            FF, EMB, EMB, EMB, FF);
        // mlp proj: 256^2 8-phase split-K x4 -> 192 blocks, fp32 partials
        gemm8<6, 4><<<dim3(EMB / 256, BT / 256, 4), 512, 0, stream>>>(
            fcout, wT_mp + (size_t)l * EMB * FF, nullptr, nullptr, pbuf,
            EMB, FF, FF, FF, EMB);
        const float* ng = (l < N_LAYER - 1) ? (ln1_g + (l + 1) * EMB) : lnf_g;
        const float* nb2 = (l < N_LAYER - 1) ? (ln1_b + (l + 1) * EMB) : lnf_b;
        reduce_ln_kernel<4><<<BT, 256, 0, stream>>>(
            pbuf, mlp_proj_b + l * EMB, h, ng, nb2, xb);
    }
    // head: split-K x8 -> 256 blocks, scalar fp32 partials + reduce with bias
    gemm_bt<7, 8><<<dim3(1, BT / 128, 8), 256, 0, stream>>>(
        xb, wT_head, nullptr, nullptr, pbuf,
        BT, VOC, EMB, EMB, EMB, VOC);
    reduce_head_kernel<<<(BT * VOC) / 256, 256, 0, stream>>>(pbuf, head_b, out);
}

// Round 7
// 2652.276 us; speedup vs baseline: 1.5107x; 1.5107x over previous
//
#include <hip/hip_runtime.h>
#include <cmath>

using bf16 = __bf16;
typedef __bf16 bf16x8 __attribute__((ext_vector_type(8)));
typedef float f32x4 __attribute__((ext_vector_type(4)));

#define N_LAYER 12
#define EMB 768
#define E3 2304
#define FF 3072
#define SEQ 512
#define NB 8
#define BT 4096
#define NH 12
#define HD 64
#define VOC 60
#define DST 128

// ---------------- async global->LDS, 16B per lane ----------------
__device__ __forceinline__ void gll16(const bf16* g, bf16* l) {
    __builtin_amdgcn_global_load_lds(
        (const __attribute__((address_space(1))) void*)g,
        (__attribute__((address_space(3))) void*)l,
        16, 0, 0);
}

// ---------------- XCD-aware bijective block remap (requires nwg % 8 == 0) ----------------
__device__ __forceinline__ void xcd_remap(int& bx, int& by, int& bz)
{
    int gx = gridDim.x, gy = gridDim.y, gz = gridDim.z;
    int nwg = gx * gy * gz;
    int lin = (blockIdx.z * gy + blockIdx.y) * gx + blockIdx.x;
    int swz = (lin & 7) * (nwg >> 3) + (lin >> 3);
    bx = swz % gx;
    int t = swz / gx;
    by = t % gy;
    bz = t / gy;
}

// ---------------- state scan ----------------
__global__ __launch_bounds__(1024)
void scan_kernel(const int* __restrict__ ids, const int* __restrict__ mul, int* __restrict__ pre)
{
    __shared__ int smul[VOC * VOC];
    __shared__ int sx[SEQ];
    __shared__ int chunk_end[16 * VOC];
    __shared__ int entry[17];
    int b = blockIdx.x;
    int tid = threadIdx.x;
    for (int i = tid; i < VOC * VOC; i += 1024) smul[i] = mul[i];
    for (int i = tid; i < SEQ; i += 1024) sx[i] = ids[b * SEQ + i];
    __syncthreads();
    if (tid < 16 * VOC) {
        int c = tid / VOC, s0 = tid % VOC;
        int s = s0;
        int base = c * 32;
        for (int j = 0; j < 32; j++) s = smul[sx[base + j] * VOC + s];
        chunk_end[c * VOC + s0] = s;
    }
    __syncthreads();
    if (tid == 0) {
        int s = 0; // ID_ID
        entry[0] = 0;
        for (int c = 0; c < 16; c++) { s = chunk_end[c * VOC + s]; entry[c + 1] = s; }
    }
    __syncthreads();
    if (tid < 16) {
        int c = tid;
        int s = entry[c];
        for (int j = 0; j < 32; j++) {
            int t = c * 32 + j;
            pre[b * SEQ + t] = s;
            s = smul[sx[t] * VOC + s];
        }
    }
}

// ---------------- state-emb projection table: pst[v][e] ----------------
__global__ __launch_bounds__(256)
void pst_kernel(const float* __restrict__ se, const float* __restrict__ w,
                const float* __restrict__ bias, float* __restrict__ pst)
{
    int v = blockIdx.x;
    int e = blockIdx.y * 256 + threadIdx.x;
    float acc = bias[e];
    for (int k = 0; k < DST; k++) acc += se[v * DST + k] * w[k * EMB + e];
    pst[v * EMB + e] = acc;
}

// ---------------- cross-wave LN stats reduce helper (256 threads) ----------------
__device__ __forceinline__ void ln_stats(float& s, float& s2, float* ps, int tid)
{
    for (int o = 32; o > 0; o >>= 1) { s += __shfl_xor(s, o, 64); s2 += __shfl_xor(s2, o, 64); }
    int wave = tid >> 6, lane = tid & 63;
    if (lane == 0) { ps[wave] = s; ps[4 + wave] = s2; }
    __syncthreads();
    s = ps[0] + ps[1] + ps[2] + ps[3];
    s2 = ps[4] + ps[5] + ps[6] + ps[7];
}

// ---------------- fused embedding + LN: h, xb = LN(emb) ----------------
__global__ __launch_bounds__(256)
void embed_ln_kernel(const int* __restrict__ ids, const int* __restrict__ pre,
                     const float* __restrict__ tok_emb, const float* __restrict__ pst,
                     const float* __restrict__ wpe,
                     const float* __restrict__ g, const float* __restrict__ b,
                     float* __restrict__ h, bf16* __restrict__ y)
{
    int t = blockIdx.x;                 // token index
    int pos = t & (SEQ - 1);
    int id = ids[t], pr = pre[t];
    int tid = threadIdx.x;
    float vals[3];
    float s = 0.f, s2 = 0.f;
    for (int j = 0; j < 3; j++) {
        int e = tid + j * 256;
        float xv = tok_emb[id * EMB + e] + pst[pr * EMB + e] + wpe[pos * EMB + e];
        h[(size_t)t * EMB + e] = xv;
        vals[j] = xv; s += xv; s2 += xv * xv;
    }
    __shared__ float ps[8];
    ln_stats(s, s2, ps, tid);
    float m = s * (1.0f / EMB);
    float var = s2 * (1.0f / EMB) - m * m;
    float inv = rsqrtf(var + 1e-5f);
    for (int j = 0; j < 3; j++) {
        int e = tid + j * 256;
        y[(size_t)t * EMB + e] = (bf16)((vals[j] - m) * inv * g[e] + b[e]);
    }
}

// ---------------- fused split-K reduce + residual + LN ----------------
template<int S>
__global__ __launch_bounds__(256)
void reduce_ln_kernel(const float* __restrict__ p, const float* __restrict__ bias,
                      float* __restrict__ h,
                      const float* __restrict__ g, const float* __restrict__ b,
                      bf16* __restrict__ y)
{
    int t = blockIdx.x;
    int tid = threadIdx.x;
    float vals[3];
    float s = 0.f, s2 = 0.f;
    for (int j = 0; j < 3; j++) {
        int e = tid + j * 256;
        size_t i = (size_t)t * EMB + e;
        float acc = bias[e] + h[i];
        for (int sp = 0; sp < S; sp++) acc += p[(size_t)sp * ((size_t)BT * EMB) + i];
        h[i] = acc;
        vals[j] = acc; s += acc; s2 += acc * acc;
    }
    __shared__ float ps[8];
    ln_stats(s, s2, ps, tid);
    float m = s * (1.0f / EMB);
    float var = s2 * (1.0f / EMB) - m * m;
    float inv = rsqrtf(var + 1e-5f);
    for (int j = 0; j < 3; j++) {
        int e = tid + j * 256;
        y[(size_t)t * EMB + e] = (bf16)((vals[j] - m) * inv * g[e] + b[e]);
    }
}

// ---------------- weight transpose + fp32->bf16: W[K,N] -> WT[N,K] ----------------
__global__ __launch_bounds__(256)
void convw_kernel(const float* __restrict__ W, bf16* __restrict__ WT, int K, int N)
{
    __shared__ float tile[32][33];
    int kb = blockIdx.y * 32, nb = blockIdx.x * 32;
    const float* Wl = W + (size_t)blockIdx.z * K * N;
    bf16* WTl = WT + (size_t)blockIdx.z * K * N;
    int tx = threadIdx.x & 31, ty = threadIdx.x >> 5; // ty 0..7
    for (int i = ty; i < 32; i += 8) {
        int k = kb + i, n = nb + tx;
        if (k < K && n < N) tile[i][tx] = Wl[(size_t)k * N + n];
    }
    __syncthreads();
    for (int i = ty; i < 32; i += 8) {
        int n = nb + i, k = kb + tx;
        if (k < K && n < N) WTl[(size_t)n * K + k] = (bf16)tile[tx][i];
    }
}

// ---------------- fused flash attention: qkv,vT -> o[B,T,E] (bf16) ----------------
__global__ __launch_bounds__(256)
void fattn_kernel(const bf16* __restrict__ qkv, const bf16* __restrict__ vT, bf16* __restrict__ Og)
{
    __shared__ bf16 sK[128 * 64];
    __shared__ bf16 sV[64 * 128];
    __shared__ bf16 sP[4][16 * 128];
    int mq, bh, bzu;
    xcd_remap(mq, bh, bzu);       // grid (8, 96): heads cluster per XCD for K/V L2 locality
    int b = bh / NH, hh = bh - b * NH;
    int tid = threadIdx.x, lane = tid & 63, wave = tid >> 6;
    int r = lane & 15, q = lane >> 4;

    const bf16* Qg = qkv + (size_t)(b * SEQ + mq * 64) * E3 + hh * HD;
    const bf16* Kg = qkv + (size_t)(b * SEQ) * E3 + EMB + hh * HD;
    const bf16* Vg = vT + (size_t)bh * HD * SEQ;

    bf16x8 af[2];
    {
        const bf16* qrow = Qg + (size_t)(wave * 16 + r) * E3 + q * 8;
        af[0] = *(const bf16x8*)(qrow);
        af[1] = *(const bf16x8*)(qrow + 32);
    }

    float mrun[4], lrun[4];
    f32x4 acco[4];
    for (int e = 0; e < 4; e++) { mrun[e] = -1e30f; lrun[e] = 0.f; }
    for (int no = 0; no < 4; no++)
        for (int e = 0; e < 4; e++) acco[no][e] = 0.f;

    int KT = mq / 2 + 1;   // causal: only tiles with cols <= max row
    bf16* sPw = sP[wave];

    for (int kt = 0; kt < KT; kt++) {
        {
            int row = tid >> 3;            // 0..31, 8 lanes/row
            int cb = (tid & 7) * 8;
            for (int rd = 0; rd < 4; rd++) {
                int rr = rd * 32 + row;
                bf16x8 kv = *(const bf16x8*)(Kg + (size_t)(kt * 128 + rr) * E3 + cb);
                *(bf16x8*)(sK + ((rr * 64 + cb) ^ ((rr & 7) << 3))) = kv;
            }
            int rowv = tid >> 4;           // 0..15, 16 lanes/row
            int cbv = (tid & 15) * 8;
            for (int rd = 0; rd < 4; rd++) {
                int rr = rd * 16 + rowv;
                bf16x8 vv = *(const bf16x8*)(Vg + (size_t)rr * SEQ + kt * 128 + cbv);
                *(bf16x8*)(sV + ((rr * 128 + cbv) ^ ((rr & 7) << 3))) = vv;
            }
        }
        __syncthreads();

        f32x4 acc[8];
        for (int ni = 0; ni < 8; ni++)
            for (int e = 0; e < 4; e++) acc[ni][e] = 0.f;
        for (int ks = 0; ks < 2; ks++) {
            for (int ni = 0; ni < 8; ni++) {
                int row = ni * 16 + r;
                bf16x8 bk = *(const bf16x8*)(sK + ((row * 64 + ks * 32 + q * 8) ^ ((row & 7) << 3)));
                acc[ni] = __builtin_amdgcn_mfma_f32_16x16x32_bf16(af[ks], bk, acc[ni], 0, 0, 0);
            }
        }

        bool dm = (kt * 128 + 127) > (mq * 64);
        for (int ni = 0; ni < 8; ni++) {
            int col = kt * 128 + ni * 16 + r;
            for (int e = 0; e < 4; e++) {
                float s = acc[ni][e] * 0.125f;
                if (dm) {
                    int rowg = mq * 64 + wave * 16 + q * 4 + e;
                    if (col > rowg) s = -1e30f;
                }
                acc[ni][e] = s;
            }
        }

        float corr[4];
        for (int e = 0; e < 4; e++) {
            float mx = -1e30f;
            for (int ni = 0; ni < 8; ni++) mx = fmaxf(mx, acc[ni][e]);
            for (int o2 = 1; o2 < 16; o2 <<= 1) mx = fmaxf(mx, __shfl_xor(mx, o2, 64));
            float mn = fmaxf(mrun[e], mx);
            corr[e] = __expf(mrun[e] - mn);
            mrun[e] = mn;
            float ps = 0.f;
            for (int ni = 0; ni < 8; ni++) {
                float p = __expf(acc[ni][e] - mn);
                acc[ni][e] = p;
                ps += p;
            }
            for (int o2 = 1; o2 < 16; o2 <<= 1) ps += __shfl_xor(ps, o2, 64);
            lrun[e] = lrun[e] * corr[e] + ps;
        }
        for (int no = 0; no < 4; no++)
            for (int e = 0; e < 4; e++) acco[no][e] *= corr[e];

        for (int ni = 0; ni < 8; ni++) {
            for (int e = 0; e < 4; e++) {
                int prow = q * 4 + e;
                sPw[(prow * 128 + ni * 16 + r) ^ ((prow & 7) << 3)] = (bf16)acc[ni][e];
            }
        }
        for (int ks2 = 0; ks2 < 4; ks2++) {
            bf16x8 pa = *(const bf16x8*)(sPw + ((r * 128 + ks2 * 32 + q * 8) ^ ((r & 7) << 3)));
            for (int no = 0; no < 4; no++) {
                int row = no * 16 + r;
                bf16x8 bv = *(const bf16x8*)(sV + ((row * 128 + ks2 * 32 + q * 8) ^ ((row & 7) << 3)));
                acco[no] = __builtin_amdgcn_mfma_f32_16x16x32_bf16(pa, bv, acco[no], 0, 0, 0);
            }
        }
        __syncthreads();
    }

    bf16* orow = Og + (size_t)(b * SEQ + mq * 64 + wave * 16) * EMB + hh * HD;
    for (int e = 0; e < 4; e++) {
        float inv = 1.0f / lrun[e];
        for (int no = 0; no < 4; no++)
            orow[(size_t)(q * 4 + e) * EMB + no * 16 + r] = (bf16)(acco[no][e] * inv);
    }
}

// ---------------- head reduce: out = head_b + sum_{s<8} partial[s] ----------------
__global__ __launch_bounds__(256)
void reduce_head_kernel(const float* __restrict__ p, const float* __restrict__ bias,
                        float* __restrict__ out)
{
    int i = blockIdx.x * 256 + threadIdx.x; // over BT*VOC
    int c = i % VOC;
    float acc = bias[c];
    for (int s = 0; s < 8; s++) acc += p[(size_t)s * ((size_t)BT * VOC) + i];
    out[i] = acc;
}

// ---------------- MFMA GEMM (m97 structure): C = A @ B^T(+bias), B given as [N][K] ----------------
// MODE 1: bias+gelu -> bf16     MODE 6: split-K fp32 partial store (vectorized)
// MODE 7: split-K fp32 partial store (scalar, small N)   MODE 8: bf16+bias + fused V->vT scatter
// XCD-aware block remap applied (all launch grids have nwg % 8 == 0).
template<int MODE, int KSPLIT = 1>
__global__ __launch_bounds__(256)
void gemm_bt(const bf16* __restrict__ Ag, const bf16* __restrict__ Bg,
             const float* __restrict__ bias, bf16* __restrict__ Cb, float* __restrict__ Cf,
             bf16* __restrict__ Vt,
             int M, int N, int K, int lda, int ldb, int ldc)
{
    __shared__ union { bf16 ab[2][128 * 32]; float st[4][16 * 68]; } sm;
    int bx, by, bz;
    xcd_remap(bx, by, bz);
    int zs = bz;                           // gridDim.z == KSPLIT (or 1)
    if constexpr (MODE == 6 || MODE == 7) Cf += (size_t)zs * M * ldc;

    int m0 = by * 128, n0 = bx * 128;
    int tid = threadIdx.x, lane = tid & 63, wave = tid >> 6;
    int wm = (wave >> 1) * 64, wn = (wave & 1) * 64;
    int r = lane & 15, q = lane >> 4;

    f32x4 acc[4][4];
    for (int mi = 0; mi < 4; mi++)
        for (int ni = 0; ni < 4; ni++)
            for (int e = 0; e < 4; e++) acc[mi][ni][e] = 0.f;

    bf16* la = sm.ab[0];
    bf16* lb = sm.ab[1];
    int srow = wave * 16 + (lane >> 2);
    int scol = (lane & 3) * 8;
    const bf16* pA = Ag + (size_t)(m0 + srow) * lda + scol;
    const bf16* pB = Bg + (size_t)(n0 + srow) * ldb + scol;
    bf16* lA0 = la + (wave * 16) * 32;
    bf16* lA1 = la + (wave * 16 + 64) * 32;
    bf16* lB0 = lb + (wave * 16) * 32;
    bf16* lB1 = lb + (wave * 16 + 64) * 32;
    size_t stepA = (size_t)64 * lda, stepB = (size_t)64 * ldb;

    int Kc = K / KSPLIT;
    int kbeg = zs * Kc, kend = kbeg + Kc;

    for (int k0 = kbeg; k0 < kend; k0 += 32) {
        gll16(pA + k0, lA0);
        gll16(pA + k0 + stepA, lA1);
        gll16(pB + k0, lB0);
        gll16(pB + k0 + stepB, lB1);
        __syncthreads();
        bf16x8 af[4], bq[4];
        for (int mi = 0; mi < 4; mi++) af[mi] = *(const bf16x8*)(la + (wm + mi * 16 + r) * 32 + q * 8);
        for (int ni = 0; ni < 4; ni++) bq[ni] = *(const bf16x8*)(lb + (wn + ni * 16 + r) * 32 + q * 8);
        for (int mi = 0; mi < 4; mi++)
            for (int ni = 0; ni < 4; ni++)
                acc[mi][ni] = __builtin_amdgcn_mfma_f32_16x16x32_bf16(af[mi], bq[ni], acc[mi][ni], 0, 0, 0);
        __syncthreads();
    }

    if constexpr (MODE == 7) {
        // scalar fp32 partial store (small N, unaligned ldc)
        for (int mi = 0; mi < 4; mi++) {
            for (int ni = 0; ni < 4; ni++) {
                int colg = n0 + wn + ni * 16 + r;
                if (colg >= N) continue;
                for (int e = 0; e < 4; e++) {
                    int rowg = m0 + wm + mi * 16 + q * 4 + e;
                    if (rowg >= M) continue;
                    Cf[(size_t)rowg * ldc + colg] = acc[mi][ni][e];
                }
            }
        }
        return;
    }

    const float* biasp = (MODE == 6) ? nullptr : bias;

    // vectorized epilogue: per-wave 16x68-padded LDS transpose -> coalesced 16B/lane writes
    float* st = sm.st[wave];
    for (int mi = 0; mi < 4; mi++) {
        for (int ni = 0; ni < 4; ni++)
            for (int e = 0; e < 4; e++)
                st[(q * 4 + e) * 68 + ni * 16 + r] = acc[mi][ni][e];
        asm volatile("s_waitcnt lgkmcnt(0)" ::: "memory");
        for (int it = 0; it < 2; it++) {
            int task = lane + it * 64;      // 128 tasks: 16 rows x 8 col-chunks
            int row = task >> 3, cc = (task & 7) * 8;
            f32x4 v0 = *(const f32x4*)(st + row * 68 + cc);
            f32x4 v1 = *(const f32x4*)(st + row * 68 + cc + 4);
            int colg = n0 + wn + cc;
            int rowg = m0 + wm + mi * 16 + row;
            if (biasp) {
                f32x4 b0 = *(const f32x4*)(biasp + colg);
                f32x4 b1 = *(const f32x4*)(biasp + colg + 4);
                v0 += b0; v1 += b1;
            }
            size_t off = (size_t)rowg * ldc + colg;
            if constexpr (MODE == 8) {
                bf16x8 pk;
                for (int j = 0; j < 4; j++) { pk[j] = (bf16)v0[j]; pk[4 + j] = (bf16)v1[j]; }
                *(bf16x8*)(Cb + off) = pk;
                if (colg >= 2 * EMB) {
                    // fused V transpose: vT[bh][d][t]
                    int hh = (colg - 2 * EMB) >> 6;
                    int d0 = (colg - 2 * EMB) & 63;
                    int bb = rowg >> 9, tt = rowg & 511;
                    bf16* vp = Vt + (((size_t)(bb * NH + hh) * HD + d0) * SEQ + tt);
#pragma unroll
                    for (int j = 0; j < 8; j++) vp[(size_t)j * SEQ] = pk[j];
                }
            } else if constexpr (MODE == 1) {
                float w[8];
                for (int j = 0; j < 4; j++) { w[j] = v0[j]; w[4 + j] = v1[j]; }
                bf16x8 pk;
                for (int j = 0; j < 8; j++) {
                    float x = w[j];
                    float gx = 0.5f * x * (1.0f + tanhf(0.7978845608028654f * (x + 0.044715f * x * x * x)));
                    pk[j] = (bf16)gx;
                }
                *(bf16x8*)(Cb + off) = pk;
            } else { // MODE 6: plain fp32 partial store
                *(f32x4*)(Cf + off) = v0;
                *(f32x4*)(Cf + off + 4) = v1;
            }
        }
        asm volatile("s_waitcnt lgkmcnt(0)" ::: "memory");
    }
}

extern "C" void kernel_launch(void* const* d_in, const int* in_sizes, int n_in,
                              void* d_out, int out_size, void* d_ws, size_t ws_size,
                              hipStream_t stream)
{
    (void)in_sizes; (void)n_in; (void)out_size; (void)ws_size;
    const int*   input_ids    = (const int*)d_in[0];
    const int*   mul          = (const int*)d_in[1];
    const float* tok_emb      = (const float*)d_in[2];
    const float* state_emb    = (const float*)d_in[3];
    const float* state_proj_w = (const float*)d_in[4];
    const float* state_proj_b = (const float*)d_in[5];
    const float* wpe          = (const float*)d_in[6];
    const float* ln1_g        = (const float*)d_in[7];
    const float* ln1_b        = (const float*)d_in[8];
    const float* attn_w       = (const float*)d_in[9];
    const float* attn_b       = (const float*)d_in[10];
    const float* attn_proj_w  = (const float*)d_in[11];
    const float* attn_proj_b  = (const float*)d_in[12];
    const float* ln2_g        = (const float*)d_in[13];
    const float* ln2_b        = (const float*)d_in[14];
    const float* fc_w         = (const float*)d_in[15];
    const float* fc_b         = (const float*)d_in[16];
    const float* mlp_proj_w   = (const float*)d_in[17];
    const float* mlp_proj_b   = (const float*)d_in[18];
    const float* lnf_g        = (const float*)d_in[19];
    const float* lnf_b        = (const float*)d_in[20];
    const float* head_w       = (const float*)d_in[21];
    const float* head_b       = (const float*)d_in[22];
    float* out = (float*)d_out;

    char* ws = (char*)d_ws;
    size_t off = 0;
    auto alloc = [&](size_t bytes) -> char* {
        char* p = ws + off;
        off += (bytes + 255) & ~(size_t)255;
        return p;
    };
    bf16*  wT_attn = (bf16*)alloc((size_t)N_LAYER * E3 * EMB * 2);
    bf16*  wT_ap   = (bf16*)alloc((size_t)N_LAYER * EMB * EMB * 2);
    bf16*  wT_fc   = (bf16*)alloc((size_t)N_LAYER * FF * EMB * 2);
    bf16*  wT_mp   = (bf16*)alloc((size_t)N_LAYER * EMB * FF * 2);
    bf16*  wT_head = (bf16*)alloc((size_t)VOC * EMB * 2);
    float* pst     = (float*)alloc((size_t)VOC * EMB * 4);
    int*   pre     = (int*)alloc((size_t)BT * 4);
    float* h       = (float*)alloc((size_t)BT * EMB * 4);
    bf16*  xb      = (bf16*)alloc((size_t)BT * EMB * 2);
    bf16*  qkv     = (bf16*)alloc((size_t)BT * E3 * 2);
    bf16*  vT      = (bf16*)alloc((size_t)NB * NH * HD * SEQ * 2);
    bf16*  o       = (bf16*)alloc((size_t)BT * EMB * 2);
    bf16*  fcout   = (bf16*)alloc((size_t)BT * FF * 2);
    float* pbuf    = (float*)alloc((size_t)4 * BT * EMB * 4);  // split-K partials (head: 8*BT*VOC fits too)

    // one-time per call: weight transpose+convert
    convw_kernel<<<dim3(E3 / 32, EMB / 32, N_LAYER), 256, 0, stream>>>(attn_w, wT_attn, EMB, E3);
    convw_kernel<<<dim3(EMB / 32, EMB / 32, N_LAYER), 256, 0, stream>>>(attn_proj_w, wT_ap, EMB, EMB);
    convw_kernel<<<dim3(FF / 32, EMB / 32, N_LAYER), 256, 0, stream>>>(fc_w, wT_fc, EMB, FF);
    convw_kernel<<<dim3(EMB / 32, FF / 32, N_LAYER), 256, 0, stream>>>(mlp_proj_w, wT_mp, FF, EMB);
    convw_kernel<<<dim3(2, EMB / 32, 1), 256, 0, stream>>>(head_w, wT_head, EMB, VOC);

    scan_kernel<<<NB, 1024, 0, stream>>>(input_ids, mul, pre);
    pst_kernel<<<dim3(VOC, 3), 256, 0, stream>>>(state_emb, state_proj_w, state_proj_b, pst);
    // fused embed + ln1(layer 0)
    embed_ln_kernel<<<BT, 256, 0, stream>>>(input_ids, pre, tok_emb, pst, wpe,
                                            ln1_g, ln1_b, h, xb);

    for (int l = 0; l < N_LAYER; l++) {
        // QKV (+ fused V->vT transpose in epilogue): 576 blocks
        gemm_bt<8><<<dim3(E3 / 128, BT / 128, 1), 256, 0, stream>>>(
            xb, wT_attn + (size_t)l * E3 * EMB, attn_b + l * E3, qkv, nullptr, vT,
            BT, E3, EMB, EMB, EMB, E3);
        fattn_kernel<<<dim3(SEQ / 64, NB * NH), 256, 0, stream>>>(qkv, vT, o);
        // attn proj: split-K x4 -> 768 blocks, fp32 partials
        gemm_bt<6, 4><<<dim3(EMB / 128, BT / 128, 4), 256, 0, stream>>>(
            o, wT_ap + (size_t)l * EMB * EMB, nullptr, nullptr, pbuf, nullptr,
            BT, EMB, EMB, EMB, EMB, EMB);
        reduce_ln_kernel<4><<<BT, 256, 0, stream>>>(
            pbuf, attn_proj_b + l * EMB, h, ln2_g + l * EMB, ln2_b + l * EMB, xb);
        // fc + gelu: 768 blocks
        gemm_bt<1><<<dim3(FF / 128, BT / 128, 1), 256, 0, stream>>>(
            xb, wT_fc + (size_t)l * FF * EMB, fc_b + l * FF, fcout, nullptr, nullptr,
            BT, FF, EMB, EMB, EMB, FF);
        // mlp proj: split-K x4 -> 768 blocks, fp32 partials
        gemm_bt<6, 4><<<dim3(EMB / 128, BT / 128, 4), 256, 0, stream>>>(
            fcout, wT_mp + (size_t)l * EMB * FF, nullptr, nullptr, pbuf, nullptr,
            BT, EMB, FF, FF, FF, EMB);
        const float* ng = (l < N_LAYER - 1) ? (ln1_g + (l + 1) * EMB) : lnf_g;
        const float* nb2 = (l < N_LAYER - 1) ? (ln1_b + (l + 1) * EMB) : lnf_b;
        reduce_ln_kernel<4><<<BT, 256, 0, stream>>>(
            pbuf, mlp_proj_b + l * EMB, h, ng, nb2, xb);
    }
    // head: split-K x8 -> 256 blocks, scalar fp32 partials + reduce with bias
    gemm_bt<7, 8><<<dim3(1, BT / 128, 8), 256, 0, stream>>>(
        xb, wT_head, nullptr, nullptr, pbuf, nullptr,
        BT, VOC, EMB, EMB, EMB, VOC);
    reduce_head_kernel<<<(BT * VOC) / 256, 256, 0, stream>>>(pbuf, head_b, out);
}

// Round 8
// 2626.997 us; speedup vs baseline: 1.5253x; 1.0096x over previous
//
#include <hip/hip_runtime.h>
#include <cmath>

using bf16 = __bf16;
typedef __bf16 bf16x8 __attribute__((ext_vector_type(8)));
typedef __bf16 bf16x4 __attribute__((ext_vector_type(4)));
typedef float f32x4 __attribute__((ext_vector_type(4)));

#define N_LAYER 12
#define EMB 768
#define E3 2304
#define FF 3072
#define SEQ 512
#define NB 8
#define BT 4096
#define NH 12
#define HD 64
#define VOC 60
#define DST 128

// ---------------- async global->LDS, 16B per lane ----------------
__device__ __forceinline__ void gll16(const bf16* g, bf16* l) {
    __builtin_amdgcn_global_load_lds(
        (const __attribute__((address_space(1))) void*)g,
        (__attribute__((address_space(3))) void*)l,
        16, 0, 0);
}

// ---------------- XCD-aware bijective block remap (requires nwg % 8 == 0) ----------------
__device__ __forceinline__ void xcd_remap(int& bx, int& by, int& bz)
{
    int gx = gridDim.x, gy = gridDim.y, gz = gridDim.z;
    int nwg = gx * gy * gz;
    int lin = (blockIdx.z * gy + blockIdx.y) * gx + blockIdx.x;
    int swz = (lin & 7) * (nwg >> 3) + (lin >> 3);
    bx = swz % gx;
    int t = swz / gx;
    by = t % gy;
    bz = t / gy;
}

// ---------------- state scan ----------------
__global__ __launch_bounds__(1024)
void scan_kernel(const int* __restrict__ ids, const int* __restrict__ mul, int* __restrict__ pre)
{
    __shared__ int smul[VOC * VOC];
    __shared__ int sx[SEQ];
    __shared__ int chunk_end[16 * VOC];
    __shared__ int entry[17];
    int b = blockIdx.x;
    int tid = threadIdx.x;
    for (int i = tid; i < VOC * VOC; i += 1024) smul[i] = mul[i];
    for (int i = tid; i < SEQ; i += 1024) sx[i] = ids[b * SEQ + i];
    __syncthreads();
    if (tid < 16 * VOC) {
        int c = tid / VOC, s0 = tid % VOC;
        int s = s0;
        int base = c * 32;
        for (int j = 0; j < 32; j++) s = smul[sx[base + j] * VOC + s];
        chunk_end[c * VOC + s0] = s;
    }
    __syncthreads();
    if (tid == 0) {
        int s = 0; // ID_ID
        entry[0] = 0;
        for (int c = 0; c < 16; c++) { s = chunk_end[c * VOC + s]; entry[c + 1] = s; }
    }
    __syncthreads();
    if (tid < 16) {
        int c = tid;
        int s = entry[c];
        for (int j = 0; j < 32; j++) {
            int t = c * 32 + j;
            pre[b * SEQ + t] = s;
            s = smul[sx[t] * VOC + s];
        }
    }
}

// ---------------- state-emb projection table: pst[v][e] ----------------
__global__ __launch_bounds__(256)
void pst_kernel(const float* __restrict__ se, const float* __restrict__ w,
                const float* __restrict__ bias, float* __restrict__ pst)
{
    int v = blockIdx.x;
    int e = blockIdx.y * 256 + threadIdx.x;
    float acc = bias[e];
    for (int k = 0; k < DST; k++) acc += se[v * DST + k] * w[k * EMB + e];
    pst[v * EMB + e] = acc;
}

// ---------------- cross-wave LN stats reduce helper (256 threads) ----------------
__device__ __forceinline__ void ln_stats(float& s, float& s2, float* ps, int tid)
{
    for (int o = 32; o > 0; o >>= 1) { s += __shfl_xor(s, o, 64); s2 += __shfl_xor(s2, o, 64); }
    int wave = tid >> 6, lane = tid & 63;
    if (lane == 0) { ps[wave] = s; ps[4 + wave] = s2; }
    __syncthreads();
    s = ps[0] + ps[1] + ps[2] + ps[3];
    s2 = ps[4] + ps[5] + ps[6] + ps[7];
}

// ---------------- fused embedding + LN: h, xb = LN(emb) ----------------
__global__ __launch_bounds__(256)
void embed_ln_kernel(const int* __restrict__ ids, const int* __restrict__ pre,
                     const float* __restrict__ tok_emb, const float* __restrict__ pst,
                     const float* __restrict__ wpe,
                     const float* __restrict__ g, const float* __restrict__ b,
                     float* __restrict__ h, bf16* __restrict__ y)
{
    int t = blockIdx.x;                 // token index
    int pos = t & (SEQ - 1);
    int id = ids[t], pr = pre[t];
    int tid = threadIdx.x;
    float vals[3];
    float s = 0.f, s2 = 0.f;
    for (int j = 0; j < 3; j++) {
        int e = tid + j * 256;
        float xv = tok_emb[id * EMB + e] + pst[pr * EMB + e] + wpe[pos * EMB + e];
        h[(size_t)t * EMB + e] = xv;
        vals[j] = xv; s += xv; s2 += xv * xv;
    }
    __shared__ float ps[8];
    ln_stats(s, s2, ps, tid);
    float m = s * (1.0f / EMB);
    float var = s2 * (1.0f / EMB) - m * m;
    float inv = rsqrtf(var + 1e-5f);
    for (int j = 0; j < 3; j++) {
        int e = tid + j * 256;
        y[(size_t)t * EMB + e] = (bf16)((vals[j] - m) * inv * g[e] + b[e]);
    }
}

// ---------------- fused split-K reduce + residual + LN (vectorized f32x4) ----------------
// threads 0..191 each own 4 cols; h[t] += bias + sum_s p[s][t]; y[t] = LN(h[t])
template<int S, bool WRITE_H>
__global__ __launch_bounds__(256)
void reduce_ln_kernel(const float* __restrict__ p, const float* __restrict__ bias,
                      float* __restrict__ h,
                      const float* __restrict__ g, const float* __restrict__ b,
                      bf16* __restrict__ y)
{
    int t = blockIdx.x;
    int tid = threadIdx.x;
    int col = tid * 4;
    bool act = col < EMB;
    f32x4 v;
    for (int e = 0; e < 4; e++) v[e] = 0.f;
    float s = 0.f, s2 = 0.f;
    size_t i = (size_t)t * EMB + col;
    if (act) {
        v = *(const f32x4*)(h + i);
        v += *(const f32x4*)(bias + col);
        for (int sp = 0; sp < S; sp++)
            v += *(const f32x4*)(p + (size_t)sp * ((size_t)BT * EMB) + i);
        if (WRITE_H) *(f32x4*)(h + i) = v;
        for (int e = 0; e < 4; e++) { s += v[e]; s2 += v[e] * v[e]; }
    }
    __shared__ float ps[8];
    ln_stats(s, s2, ps, tid);
    float m = s * (1.0f / EMB);
    float var = s2 * (1.0f / EMB) - m * m;
    float inv = rsqrtf(var + 1e-5f);
    if (act) {
        f32x4 gv = *(const f32x4*)(g + col);
        f32x4 bv = *(const f32x4*)(b + col);
        bf16x4 pk;
        for (int e = 0; e < 4; e++) pk[e] = (bf16)((v[e] - m) * inv * gv[e] + bv[e]);
        *(bf16x4*)(y + i) = pk;
    }
}

// ---------------- weight transpose + fp32->bf16: W[K,N] -> WT[N,K] ----------------
__global__ __launch_bounds__(256)
void convw_kernel(const float* __restrict__ W, bf16* __restrict__ WT, int K, int N)
{
    __shared__ float tile[32][33];
    int kb = blockIdx.y * 32, nb = blockIdx.x * 32;
    const float* Wl = W + (size_t)blockIdx.z * K * N;
    bf16* WTl = WT + (size_t)blockIdx.z * K * N;
    int tx = threadIdx.x & 31, ty = threadIdx.x >> 5; // ty 0..7
    for (int i = ty; i < 32; i += 8) {
        int k = kb + i, n = nb + tx;
        if (k < K && n < N) tile[i][tx] = Wl[(size_t)k * N + n];
    }
    __syncthreads();
    for (int i = ty; i < 32; i += 8) {
        int n = nb + i, k = kb + tx;
        if (k < K && n < N) WTl[(size_t)n * K + k] = (bf16)tile[tx][i];
    }
}

// ---------------- fused flash attention: qkv,vT -> o[B,T,E] (bf16) ----------------
__global__ __launch_bounds__(256)
void fattn_kernel(const bf16* __restrict__ qkv, const bf16* __restrict__ vT, bf16* __restrict__ Og)
{
    __shared__ bf16 sK[128 * 64];
    __shared__ bf16 sV[64 * 128];
    __shared__ bf16 sP[4][16 * 128];
    int mq, bh, bzu;
    xcd_remap(mq, bh, bzu);       // grid (8, 96): heads cluster per XCD for K/V L2 locality
    int b = bh / NH, hh = bh - b * NH;
    int tid = threadIdx.x, lane = tid & 63, wave = tid >> 6;
    int r = lane & 15, q = lane >> 4;

    const bf16* Qg = qkv + (size_t)(b * SEQ + mq * 64) * E3 + hh * HD;
    const bf16* Kg = qkv + (size_t)(b * SEQ) * E3 + EMB + hh * HD;
    const bf16* Vg = vT + (size_t)bh * HD * SEQ;

    bf16x8 af[2];
    {
        const bf16* qrow = Qg + (size_t)(wave * 16 + r) * E3 + q * 8;
        af[0] = *(const bf16x8*)(qrow);
        af[1] = *(const bf16x8*)(qrow + 32);
    }

    float mrun[4], lrun[4];
    f32x4 acco[4];
    for (int e = 0; e < 4; e++) { mrun[e] = -1e30f; lrun[e] = 0.f; }
    for (int no = 0; no < 4; no++)
        for (int e = 0; e < 4; e++) acco[no][e] = 0.f;

    int KT = mq / 2 + 1;   // causal: only tiles with cols <= max row
    bf16* sPw = sP[wave];

    for (int kt = 0; kt < KT; kt++) {
        {
            int row = tid >> 3;            // 0..31, 8 lanes/row
            int cb = (tid & 7) * 8;
            for (int rd = 0; rd < 4; rd++) {
                int rr = rd * 32 + row;
                bf16x8 kv = *(const bf16x8*)(Kg + (size_t)(kt * 128 + rr) * E3 + cb);
                *(bf16x8*)(sK + ((rr * 64 + cb) ^ ((rr & 7) << 3))) = kv;
            }
            int rowv = tid >> 4;           // 0..15, 16 lanes/row
            int cbv = (tid & 15) * 8;
            for (int rd = 0; rd < 4; rd++) {
                int rr = rd * 16 + rowv;
                bf16x8 vv = *(const bf16x8*)(Vg + (size_t)rr * SEQ + kt * 128 + cbv);
                *(bf16x8*)(sV + ((rr * 128 + cbv) ^ ((rr & 7) << 3))) = vv;
            }
        }
        __syncthreads();

        f32x4 acc[8];
        for (int ni = 0; ni < 8; ni++)
            for (int e = 0; e < 4; e++) acc[ni][e] = 0.f;
        for (int ks = 0; ks < 2; ks++) {
            for (int ni = 0; ni < 8; ni++) {
                int row = ni * 16 + r;
                bf16x8 bk = *(const bf16x8*)(sK + ((row * 64 + ks * 32 + q * 8) ^ ((row & 7) << 3)));
                acc[ni] = __builtin_amdgcn_mfma_f32_16x16x32_bf16(af[ks], bk, acc[ni], 0, 0, 0);
            }
        }

        bool dm = (kt * 128 + 127) > (mq * 64);
        for (int ni = 0; ni < 8; ni++) {
            int col = kt * 128 + ni * 16 + r;
            for (int e = 0; e < 4; e++) {
                float s = acc[ni][e] * 0.125f;
                if (dm) {
                    int rowg = mq * 64 + wave * 16 + q * 4 + e;
                    if (col > rowg) s = -1e30f;
                }
                acc[ni][e] = s;
            }
        }

        float corr[4];
        for (int e = 0; e < 4; e++) {
            float mx = -1e30f;
            for (int ni = 0; ni < 8; ni++) mx = fmaxf(mx, acc[ni][e]);
            for (int o2 = 1; o2 < 16; o2 <<= 1) mx = fmaxf(mx, __shfl_xor(mx, o2, 64));
            float mn = fmaxf(mrun[e], mx);
            corr[e] = __expf(mrun[e] - mn);
            mrun[e] = mn;
            float ps = 0.f;
            for (int ni = 0; ni < 8; ni++) {
                float p = __expf(acc[ni][e] - mn);
                acc[ni][e] = p;
                ps += p;
            }
            for (int o2 = 1; o2 < 16; o2 <<= 1) ps += __shfl_xor(ps, o2, 64);
            lrun[e] = lrun[e] * corr[e] + ps;
        }
        for (int no = 0; no < 4; no++)
            for (int e = 0; e < 4; e++) acco[no][e] *= corr[e];

        for (int ni = 0; ni < 8; ni++) {
            for (int e = 0; e < 4; e++) {
                int prow = q * 4 + e;
                sPw[(prow * 128 + ni * 16 + r) ^ ((prow & 7) << 3)] = (bf16)acc[ni][e];
            }
        }
        for (int ks2 = 0; ks2 < 4; ks2++) {
            bf16x8 pa = *(const bf16x8*)(sPw + ((r * 128 + ks2 * 32 + q * 8) ^ ((r & 7) << 3)));
            for (int no = 0; no < 4; no++) {
                int row = no * 16 + r;
                bf16x8 bv = *(const bf16x8*)(sV + ((row * 128 + ks2 * 32 + q * 8) ^ ((row & 7) << 3)));
                acco[no] = __builtin_amdgcn_mfma_f32_16x16x32_bf16(pa, bv, acco[no], 0, 0, 0);
            }
        }
        __syncthreads();
    }

    bf16* orow = Og + (size_t)(b * SEQ + mq * 64 + wave * 16) * EMB + hh * HD;
    for (int e = 0; e < 4; e++) {
        float inv = 1.0f / lrun[e];
        for (int no = 0; no < 4; no++)
            orow[(size_t)(q * 4 + e) * EMB + no * 16 + r] = (bf16)(acco[no][e] * inv);
    }
}

// ---------------- head reduce: out = head_b + sum_{s<8} partial[s] ----------------
__global__ __launch_bounds__(256)
void reduce_head_kernel(const float* __restrict__ p, const float* __restrict__ bias,
                        float* __restrict__ out)
{
    int i = blockIdx.x * 256 + threadIdx.x; // over BT*VOC
    int c = i % VOC;
    float acc = bias[c];
    for (int s = 0; s < 8; s++) acc += p[(size_t)s * ((size_t)BT * VOC) + i];
    out[i] = acc;
}

// ---------------- MFMA GEMM (m97 structure): C = A @ B^T(+bias), B given as [N][K] ----------------
// MODE 1: bias+gelu -> bf16     MODE 6: split-K fp32 partial store (vectorized)
// MODE 7: split-K fp32 partial store (scalar, small N)   MODE 8: bf16+bias + fused V->vT scatter
// XCD-aware block remap applied (all launch grids have nwg % 8 == 0).
template<int MODE, int KSPLIT = 1>
__global__ __launch_bounds__(256)
void gemm_bt(const bf16* __restrict__ Ag, const bf16* __restrict__ Bg,
             const float* __restrict__ bias, bf16* __restrict__ Cb, float* __restrict__ Cf,
             bf16* __restrict__ Vt,
             int M, int N, int K, int lda, int ldb, int ldc)
{
    __shared__ union { bf16 ab[2][128 * 32]; float st[4][16 * 68]; } sm;
    int bx, by, bz;
    xcd_remap(bx, by, bz);
    int zs = bz;                           // gridDim.z == KSPLIT (or 1)
    if constexpr (MODE == 6 || MODE == 7) Cf += (size_t)zs * M * ldc;

    int m0 = by * 128, n0 = bx * 128;
    int tid = threadIdx.x, lane = tid & 63, wave = tid >> 6;
    int wm = (wave >> 1) * 64, wn = (wave & 1) * 64;
    int r = lane & 15, q = lane >> 4;

    f32x4 acc[4][4];
    for (int mi = 0; mi < 4; mi++)
        for (int ni = 0; ni < 4; ni++)
            for (int e = 0; e < 4; e++) acc[mi][ni][e] = 0.f;

    bf16* la = sm.ab[0];
    bf16* lb = sm.ab[1];
    int srow = wave * 16 + (lane >> 2);
    int scol = (lane & 3) * 8;
    const bf16* pA = Ag + (size_t)(m0 + srow) * lda + scol;
    const bf16* pB = Bg + (size_t)(n0 + srow) * ldb + scol;
    bf16* lA0 = la + (wave * 16) * 32;
    bf16* lA1 = la + (wave * 16 + 64) * 32;
    bf16* lB0 = lb + (wave * 16) * 32;
    bf16* lB1 = lb + (wave * 16 + 64) * 32;
    size_t stepA = (size_t)64 * lda, stepB = (size_t)64 * ldb;

    int Kc = K / KSPLIT;
    int kbeg = zs * Kc, kend = kbeg + Kc;

    for (int k0 = kbeg; k0 < kend; k0 += 32) {
        gll16(pA + k0, lA0);
        gll16(pA + k0 + stepA, lA1);
        gll16(pB + k0, lB0);
        gll16(pB + k0 + stepB, lB1);
        __syncthreads();
        bf16x8 af[4], bq[4];
        for (int mi = 0; mi < 4; mi++) af[mi] = *(const bf16x8*)(la + (wm + mi * 16 + r) * 32 + q * 8);
        for (int ni = 0; ni < 4; ni++) bq[ni] = *(const bf16x8*)(lb + (wn + ni * 16 + r) * 32 + q * 8);
        for (int mi = 0; mi < 4; mi++)
            for (int ni = 0; ni < 4; ni++)
                acc[mi][ni] = __builtin_amdgcn_mfma_f32_16x16x32_bf16(af[mi], bq[ni], acc[mi][ni], 0, 0, 0);
        __syncthreads();
    }

    if constexpr (MODE == 7) {
        // scalar fp32 partial store (small N, unaligned ldc)
        for (int mi = 0; mi < 4; mi++) {
            for (int ni = 0; ni < 4; ni++) {
                int colg = n0 + wn + ni * 16 + r;
                if (colg >= N) continue;
                for (int e = 0; e < 4; e++) {
                    int rowg = m0 + wm + mi * 16 + q * 4 + e;
                    if (rowg >= M) continue;
                    Cf[(size_t)rowg * ldc + colg] = acc[mi][ni][e];
                }
            }
        }
        return;
    }

    const float* biasp = (MODE == 6) ? nullptr : bias;

    // vectorized epilogue: per-wave 16x68-padded LDS transpose -> coalesced 16B/lane writes
    float* st = sm.st[wave];
    for (int mi = 0; mi < 4; mi++) {
        for (int ni = 0; ni < 4; ni++)
            for (int e = 0; e < 4; e++)
                st[(q * 4 + e) * 68 + ni * 16 + r] = acc[mi][ni][e];
        asm volatile("s_waitcnt lgkmcnt(0)" ::: "memory");
        for (int it = 0; it < 2; it++) {
            int task = lane + it * 64;      // 128 tasks: 16 rows x 8 col-chunks
            int row = task >> 3, cc = (task & 7) * 8;
            f32x4 v0 = *(const f32x4*)(st + row * 68 + cc);
            f32x4 v1 = *(const f32x4*)(st + row * 68 + cc + 4);
            int colg = n0 + wn + cc;
            int rowg = m0 + wm + mi * 16 + row;
            if (biasp) {
                f32x4 b0 = *(const f32x4*)(biasp + colg);
                f32x4 b1 = *(const f32x4*)(biasp + colg + 4);
                v0 += b0; v1 += b1;
            }
            size_t off = (size_t)rowg * ldc + colg;
            if constexpr (MODE == 8) {
                bf16x8 pk;
                for (int j = 0; j < 4; j++) { pk[j] = (bf16)v0[j]; pk[4 + j] = (bf16)v1[j]; }
                *(bf16x8*)(Cb + off) = pk;
                if (colg >= 2 * EMB) {
                    // fused V transpose: vT[bh][d][t]
                    int hh = (colg - 2 * EMB) >> 6;
                    int d0 = (colg - 2 * EMB) & 63;
                    int bb = rowg >> 9, tt = rowg & 511;
                    bf16* vp = Vt + (((size_t)(bb * NH + hh) * HD + d0) * SEQ + tt);
#pragma unroll
                    for (int j = 0; j < 8; j++) vp[(size_t)j * SEQ] = pk[j];
                }
            } else if constexpr (MODE == 1) {
                float w[8];
                for (int j = 0; j < 4; j++) { w[j] = v0[j]; w[4 + j] = v1[j]; }
                bf16x8 pk;
                for (int j = 0; j < 8; j++) {
                    float x = w[j];
                    float gx = 0.5f * x * (1.0f + tanhf(0.7978845608028654f * (x + 0.044715f * x * x * x)));
                    pk[j] = (bf16)gx;
                }
                *(bf16x8*)(Cb + off) = pk;
            } else { // MODE 6: plain fp32 partial store
                *(f32x4*)(Cf + off) = v0;
                *(f32x4*)(Cf + off + 4) = v1;
            }
        }
        asm volatile("s_waitcnt lgkmcnt(0)" ::: "memory");
    }
}

extern "C" void kernel_launch(void* const* d_in, const int* in_sizes, int n_in,
                              void* d_out, int out_size, void* d_ws, size_t ws_size,
                              hipStream_t stream)
{
    (void)in_sizes; (void)n_in; (void)out_size; (void)ws_size;
    const int*   input_ids    = (const int*)d_in[0];
    const int*   mul          = (const int*)d_in[1];
    const float* tok_emb      = (const float*)d_in[2];
    const float* state_emb    = (const float*)d_in[3];
    const float* state_proj_w = (const float*)d_in[4];
    const float* state_proj_b = (const float*)d_in[5];
    const float* wpe          = (const float*)d_in[6];
    const float* ln1_g        = (const float*)d_in[7];
    const float* ln1_b        = (const float*)d_in[8];
    const float* attn_w       = (const float*)d_in[9];
    const float* attn_b       = (const float*)d_in[10];
    const float* attn_proj_w  = (const float*)d_in[11];
    const float* attn_proj_b  = (const float*)d_in[12];
    const float* ln2_g        = (const float*)d_in[13];
    const float* ln2_b        = (const float*)d_in[14];
    const float* fc_w         = (const float*)d_in[15];
    const float* fc_b         = (const float*)d_in[16];
    const float* mlp_proj_w   = (const float*)d_in[17];
    const float* mlp_proj_b   = (const float*)d_in[18];
    const float* lnf_g        = (const float*)d_in[19];
    const float* lnf_b        = (const float*)d_in[20];
    const float* head_w       = (const float*)d_in[21];
    const float* head_b       = (const float*)d_in[22];
    float* out = (float*)d_out;

    char* ws = (char*)d_ws;
    size_t off = 0;
    auto alloc = [&](size_t bytes) -> char* {
        char* p = ws + off;
        off += (bytes + 255) & ~(size_t)255;
        return p;
    };
    bf16*  wT_attn = (bf16*)alloc((size_t)N_LAYER * E3 * EMB * 2);
    bf16*  wT_ap   = (bf16*)alloc((size_t)N_LAYER * EMB * EMB * 2);
    bf16*  wT_fc   = (bf16*)alloc((size_t)N_LAYER * FF * EMB * 2);
    bf16*  wT_mp   = (bf16*)alloc((size_t)N_LAYER * EMB * FF * 2);
    bf16*  wT_head = (bf16*)alloc((size_t)VOC * EMB * 2);
    float* pst     = (float*)alloc((size_t)VOC * EMB * 4);
    int*   pre     = (int*)alloc((size_t)BT * 4);
    float* h       = (float*)alloc((size_t)BT * EMB * 4);
    bf16*  xb      = (bf16*)alloc((size_t)BT * EMB * 2);
    bf16*  qkv     = (bf16*)alloc((size_t)BT * E3 * 2);
    bf16*  vT      = (bf16*)alloc((size_t)NB * NH * HD * SEQ * 2);
    bf16*  o       = (bf16*)alloc((size_t)BT * EMB * 2);
    bf16*  fcout   = (bf16*)alloc((size_t)BT * FF * 2);
    float* pbuf    = (float*)alloc((size_t)4 * BT * EMB * 4);  // split-K partials (head: 8*BT*VOC fits too)

    // one-time per call: weight transpose+convert
    convw_kernel<<<dim3(E3 / 32, EMB / 32, N_LAYER), 256, 0, stream>>>(attn_w, wT_attn, EMB, E3);
    convw_kernel<<<dim3(EMB / 32, EMB / 32, N_LAYER), 256, 0, stream>>>(attn_proj_w, wT_ap, EMB, EMB);
    convw_kernel<<<dim3(FF / 32, EMB / 32, N_LAYER), 256, 0, stream>>>(fc_w, wT_fc, EMB, FF);
    convw_kernel<<<dim3(EMB / 32, FF / 32, N_LAYER), 256, 0, stream>>>(mlp_proj_w, wT_mp, FF, EMB);
    convw_kernel<<<dim3(2, EMB / 32, 1), 256, 0, stream>>>(head_w, wT_head, EMB, VOC);

    scan_kernel<<<NB, 1024, 0, stream>>>(input_ids, mul, pre);
    pst_kernel<<<dim3(VOC, 3), 256, 0, stream>>>(state_emb, state_proj_w, state_proj_b, pst);
    // fused embed + ln1(layer 0)
    embed_ln_kernel<<<BT, 256, 0, stream>>>(input_ids, pre, tok_emb, pst, wpe,
                                            ln1_g, ln1_b, h, xb);

    for (int l = 0; l < N_LAYER; l++) {
        // QKV (+ fused V->vT transpose in epilogue): 576 blocks
        gemm_bt<8><<<dim3(E3 / 128, BT / 128, 1), 256, 0, stream>>>(
            xb, wT_attn + (size_t)l * E3 * EMB, attn_b + l * E3, qkv, nullptr, vT,
            BT, E3, EMB, EMB, EMB, E3);
        fattn_kernel<<<dim3(SEQ / 64, NB * NH), 256, 0, stream>>>(qkv, vT, o);
        // attn proj: split-K x2 -> 384 blocks, fp32 partials (12 K-iters/block)
        gemm_bt<6, 2><<<dim3(EMB / 128, BT / 128, 2), 256, 0, stream>>>(
            o, wT_ap + (size_t)l * EMB * EMB, nullptr, nullptr, pbuf, nullptr,
            BT, EMB, EMB, EMB, EMB, EMB);
        reduce_ln_kernel<2, true><<<BT, 256, 0, stream>>>(
            pbuf, attn_proj_b + l * EMB, h, ln2_g + l * EMB, ln2_b + l * EMB, xb);
        // fc + gelu: 768 blocks
        gemm_bt<1><<<dim3(FF / 128, BT / 128, 1), 256, 0, stream>>>(
            xb, wT_fc + (size_t)l * FF * EMB, fc_b + l * FF, fcout, nullptr, nullptr,
            BT, FF, EMB, EMB, EMB, FF);
        // mlp proj: split-K x4 -> 768 blocks, fp32 partials
        gemm_bt<6, 4><<<dim3(EMB / 128, BT / 128, 4), 256, 0, stream>>>(
            fcout, wT_mp + (size_t)l * EMB * FF, nullptr, nullptr, pbuf, nullptr,
            BT, EMB, FF, FF, FF, EMB);
        const float* ng = (l < N_LAYER - 1) ? (ln1_g + (l + 1) * EMB) : lnf_g;
        const float* nb2 = (l < N_LAYER - 1) ? (ln1_b + (l + 1) * EMB) : lnf_b;
        if (l < N_LAYER - 1)
            reduce_ln_kernel<4, true><<<BT, 256, 0, stream>>>(
                pbuf, mlp_proj_b + l * EMB, h, ng, nb2, xb);
        else  // last layer: h is dead after this; skip the h write
            reduce_ln_kernel<4, false><<<BT, 256, 0, stream>>>(
                pbuf, mlp_proj_b + l * EMB, h, ng, nb2, xb);
    }
    // head: split-K x8 -> 256 blocks, scalar fp32 partials + reduce with bias
    gemm_bt<7, 8><<<dim3(1, BT / 128, 8), 256, 0, stream>>>(
        xb, wT_head, nullptr, nullptr, pbuf, nullptr,
        BT, VOC, EMB, EMB, EMB, VOC);
    reduce_head_kernel<<<(BT * VOC) / 256, 256, 0, stream>>>(pbuf, head_b, out);
}